// Round 2
// baseline (1187.693 us; speedup 1.0000x reference)
//
#include <hip/hip_runtime.h>
#include <stdint.h>

// SAN1d: 4x { y = conv_same(x,w); a = topk_abs(y,k); out += conv_same(a,w) }
// B=64 rows, L=262144, ks={65,33,17,9}, k=L//ks.
// Strategy: exact per-(row,kernel) threshold via 8192-bin histogram on |y| bits
// + candidate radix-select; y recomputed bit-identically (same fmaf chain) in
// K1/K3/K5 so the kept set is consistent across passes.
//
// Pipeline: K1 conv+histogram -> K2 find threshold bin+rank -> K3 conv+collect
// bin-matching candidates -> K4 exact 18-bit radix select (+ stable-tie
// exception list, lowest-index-first like lax.top_k) -> K5 conv+mask+conv+sum.

#define B_ 64
#define L_ 262144
#define NBINS 8192      // |y| bits >> 18  (13 bits: exponent + 5 mantissa)
#define CAPC 8192       // candidate cap per (row,kernel); expected max ~3k
#define TSUB 2304       // 256 threads * 9 outputs
#define SUBS 8          // subtiles per K1/K3 block
#define NCHUNK 15       // ceil(L / (TSUB*SUBS))
#define T5 2304         // K5 tile
#define NT5 114         // ceil(L / T5)

typedef unsigned int u32;

__device__ const int d_K[4] = {4032, 7943, 15420, 29127};  // L_ // ks

// ---------------------------------------------------------------- K1 / K3 body
template<int KS, bool COLLECT>
__device__ __forceinline__ void conv_body(
    const float* __restrict__ x, const float* __restrict__ w,
    u32* __restrict__ ghist, const u32* __restrict__ bbin,
    u32* __restrict__ ccount, uint2* __restrict__ cand,
    float* xbuf, u32* hist)
{
  constexpr int PAD = KS / 2;
  constexpr int OFF = 32 - PAD;            // xbuf origin is base-32
  const int tid = threadIdx.x;
  const int kk  = blockIdx.y;
  const int row = blockIdx.z;
  const int rk  = row * 4 + kk;
  const float* xr = x + (size_t)row * L_;

  u32 target = 0;
  if (COLLECT) {
    target = bbin[rk];
  } else {
    for (int i = tid; i < NBINS; i += 256) hist[i] = 0u;
    __syncthreads();
  }

  for (int it = 0; it < SUBS; ++it) {
    const int base = (blockIdx.x * SUBS + it) * TSUB;
    if (base >= L_) break;                 // uniform across block
    for (int i = tid; i < TSUB + 64; i += 256) {
      int g = base - 32 + i;
      xbuf[i] = (g >= 0 && g < L_) ? xr[g] : 0.0f;   // SAME zero-pad as real taps
    }
    __syncthreads();

    float acc[9];
#pragma unroll
    for (int r = 0; r < 9; ++r) acc[r] = 0.0f;
    const int q0 = tid * 9;                // lane stride 9 (coprime 32) -> bank-clean
#pragma unroll
    for (int p = 0; p < KS + 8; ++p) {     // sliding window: p = r + j
      float xv = xbuf[q0 + OFF + p];
#pragma unroll
      for (int r = 0; r < 9; ++r) {
        const int j = p - r;
        if (j >= 0 && j < KS) acc[r] = fmaf(xv, w[j], acc[r]);  // j-ascending chain
      }
    }
#pragma unroll
    for (int r = 0; r < 9; ++r) {
      int g = base + q0 + r;
      if (g < L_) {
        u32 ab = __float_as_uint(acc[r]) & 0x7fffffffu;
        if (!COLLECT) {
          atomicAdd(&hist[ab >> 18], 1u);
        } else if ((ab >> 18) == target) {
          u32 slot = atomicAdd(&ccount[rk], 1u);
          if (slot < CAPC) cand[(size_t)rk * CAPC + slot] = make_uint2(ab, (u32)g);
        }
      }
    }
    __syncthreads();
  }

  if (!COLLECT) {
    __syncthreads();
    u32* gh = ghist + (size_t)rk * NBINS;
    for (int i = tid; i < NBINS; i += 256) {
      u32 c = hist[i];
      if (c) atomicAdd(&gh[i], c);         // skip-zero merge (device-scope)
    }
  }
}

__global__ __launch_bounds__(256) void k1_hist(
    const float* __restrict__ x, const float* __restrict__ w0,
    const float* __restrict__ w1, const float* __restrict__ w2,
    const float* __restrict__ w3, u32* __restrict__ ghist)
{
  __shared__ float xbuf[TSUB + 64];
  __shared__ u32 hist[NBINS];              // 42.2 KB total static LDS
  switch (blockIdx.y) {
    case 0:  conv_body<65, false>(x, w0, ghist, nullptr, nullptr, nullptr, xbuf, hist); break;
    case 1:  conv_body<33, false>(x, w1, ghist, nullptr, nullptr, nullptr, xbuf, hist); break;
    case 2:  conv_body<17, false>(x, w2, ghist, nullptr, nullptr, nullptr, xbuf, hist); break;
    default: conv_body< 9, false>(x, w3, ghist, nullptr, nullptr, nullptr, xbuf, hist); break;
  }
}

__global__ __launch_bounds__(256) void k3_collect(
    const float* __restrict__ x, const float* __restrict__ w0,
    const float* __restrict__ w1, const float* __restrict__ w2,
    const float* __restrict__ w3, const u32* __restrict__ bbin,
    u32* __restrict__ ccount, uint2* __restrict__ cand)
{
  __shared__ float xbuf[TSUB + 64];
  switch (blockIdx.y) {
    case 0:  conv_body<65, true>(x, w0, nullptr, bbin, ccount, cand, xbuf, nullptr); break;
    case 1:  conv_body<33, true>(x, w1, nullptr, bbin, ccount, cand, xbuf, nullptr); break;
    case 2:  conv_body<17, true>(x, w2, nullptr, bbin, ccount, cand, xbuf, nullptr); break;
    default: conv_body< 9, true>(x, w3, nullptr, bbin, ccount, cand, xbuf, nullptr); break;
  }
}

// ---------------------------------------------------------------- K2: bin find
__global__ __launch_bounds__(256) void k2_findbin(
    const u32* __restrict__ ghist, u32* __restrict__ bbin, u32* __restrict__ rrem)
{
  __shared__ u32 h[NBINS];
  __shared__ u32 ssum[256];
  const int rk = blockIdx.x;
  const u32 k = (u32)d_K[rk & 3];
  const u32* gh = ghist + (size_t)rk * NBINS;
  for (int i = threadIdx.x; i < NBINS; i += 256) h[i] = gh[i];
  __syncthreads();
  u32 s = 0;
  for (int i = 0; i < 32; ++i) s += h[threadIdx.x * 32 + i];
  ssum[threadIdx.x] = s;
  __syncthreads();
  if (threadIdx.x == 0) {
    u32 cum = 0; int b = 0;
    for (int t = 255; t >= 0; --t) {       // walk bins from the top (largest |y|)
      if (cum + ssum[t] >= k) {
        for (int i = t * 32 + 31; i >= t * 32; --i) {
          if (cum + h[i] >= k) { b = i; break; }
          cum += h[i];
        }
        break;
      }
      cum += ssum[t];
    }
    bbin[rk] = (u32)b;
    rrem[rk] = k - cum;                    // 1-based rank inside bin b
  }
}

// ---------------------------------------------------------------- K4: select
__global__ __launch_bounds__(256) void k4_select(
    const uint2* __restrict__ cand, const u32* __restrict__ ccount,
    const u32* __restrict__ bbinA, const u32* __restrict__ rremA,
    u32* __restrict__ thr, u32* __restrict__ keepAll,
    u32* __restrict__ excN, u32* __restrict__ excL)
{
  __shared__ u32 cab[CAPC];
  __shared__ u32 h64[64];
  __shared__ u32 sh[3];
  __shared__ u32 lidx[64];
  __shared__ u32 lcnt;
  const int rk = blockIdx.x;
  int n = (int)min(ccount[rk], (u32)CAPC);
  u32 r = rremA[rk];
  if (r > (u32)n) r = (u32)n;              // overflow fallback (statistically never)
  const uint2* cd = cand + (size_t)rk * CAPC;
  for (int i = threadIdx.x; i < n; i += 256) cab[i] = cd[i].x & 0x3ffffu;

  u32 sel = 0;
  for (int round = 0; round < 3; ++round) {  // 3 x 6-bit MSD radix select
    const int shift = 12 - 6 * round;
    const u32 himask = (round == 0) ? 0u : ((0x3ffffu << (shift + 6)) & 0x3ffffu);
    if (threadIdx.x < 64) h64[threadIdx.x] = 0u;
    __syncthreads();
    for (int i = threadIdx.x; i < n; i += 256) {
      u32 v = cab[i];
      if ((v & himask) == (sel & himask)) atomicAdd(&h64[(v >> shift) & 63u], 1u);
    }
    __syncthreads();
    if (threadIdx.x == 0) {
      u32 cum = 0; int d = 0;
      for (int dd = 63; dd >= 0; --dd) {
        if (cum + h64[dd] >= r) { d = dd; break; }
        cum += h64[dd];
      }
      sh[0] = (u32)d;
      sh[1] = r - cum;
      sh[2] = h64[d];
    }
    __syncthreads();
    sel |= sh[0] << shift;
    r = sh[1];
  }
  const u32 dup = sh[2];                   // multiplicity of the threshold value
  const u32 m = r;                         // how many of the tied values to keep
  if (threadIdx.x == 0) thr[rk] = (bbinA[rk] << 18) | sel;

  if (m >= dup) {
    if (threadIdx.x == 0) { keepAll[rk] = 1u; excN[rk] = 0u; }
    return;
  }
  if (threadIdx.x == 0) lcnt = 0u;
  __syncthreads();
  for (int i = threadIdx.x; i < n; i += 256) {
    if (cab[i] == sel) {
      u32 s2 = atomicAdd(&lcnt, 1u);
      if (s2 < 64) lidx[s2] = cd[i].y;
    }
  }
  __syncthreads();
  if (threadIdx.x == 0) {
    int c = (int)min(lcnt, 64u);
    for (int i = 1; i < c; ++i) {          // sort ascending index (top_k stable tie-break)
      u32 v = lidx[i]; int j = i - 1;
      while (j >= 0 && lidx[j] > v) { lidx[j + 1] = lidx[j]; --j; }
      lidx[j + 1] = v;
    }
    u32 mm = min(m, 32u);
    keepAll[rk] = 0u; excN[rk] = mm;
    for (u32 i = 0; i < mm; ++i) excL[(size_t)rk * 32 + i] = lidx[i];
  }
}

// ---------------------------------------------------------------- K5: final
template<int KS>
__device__ __forceinline__ void k5_phase(
    const float* __restrict__ w, const float* xbuf, float* ybuf, float* accO,
    int tile0, u32 t_ab, u32 kAll, u32 en, const u32* __restrict__ excLrk)
{
  constexpr int PAD = KS / 2;
  constexpr int OFF2 = 32 - PAD;
  const int tid = threadIdx.x;
  // --- recompute y on [tile0-32, tile0+T5+32), mask by threshold, store to ybuf
  const int q0 = tid * 10;
  if (q0 < T5 + 64) {
    float a[10];
#pragma unroll
    for (int r = 0; r < 10; ++r) a[r] = 0.0f;
#pragma unroll
    for (int p = 0; p < KS + 9; ++p) {
      float xv = xbuf[q0 + OFF2 + p];
#pragma unroll
      for (int r = 0; r < 10; ++r) {
        const int j = p - r;
        if (j >= 0 && j < KS) a[r] = fmaf(xv, w[j], a[r]);  // identical chain to K1/K3
      }
    }
#pragma unroll
    for (int r = 0; r < 10; ++r) {
      int q = q0 + r;
      if (q < T5 + 64) {
        int g = tile0 - 32 + q;
        float av = 0.0f;
        if (g >= 0 && g < L_) {
          float yv = a[r];
          u32 ab = __float_as_uint(yv) & 0x7fffffffu;
          bool keep = ab > t_ab;
          if (ab == t_ab) {                // threshold ties: exact top_k semantics
            if (kAll) keep = true;
            else {
              for (u32 e = 0; e < en; ++e)
                if (excLrk[e] == (u32)g) { keep = true; break; }
            }
          }
          av = keep ? yv : 0.0f;
        }
        ybuf[q] = av;
      }
    }
  }
  __syncthreads();
  // --- second conv from ybuf into accO
  {
    const int o0 = tid * 9;
#pragma unroll
    for (int p = 0; p < KS + 8; ++p) {
      float yv = ybuf[o0 + OFF2 + p];
#pragma unroll
      for (int r = 0; r < 9; ++r) {
        const int j = p - r;
        if (j >= 0 && j < KS) accO[r] = fmaf(yv, w[j], accO[r]);
      }
    }
  }
  __syncthreads();
}

__global__ __launch_bounds__(256) void k5_final(
    const float* __restrict__ x, const float* __restrict__ w0,
    const float* __restrict__ w1, const float* __restrict__ w2,
    const float* __restrict__ w3, const u32* __restrict__ thr,
    const u32* __restrict__ keepAll, const u32* __restrict__ excN,
    const u32* __restrict__ excL, float* __restrict__ out)
{
  __shared__ __align__(16) float xbuf[T5 + 160];   // [tile0-64, tile0+2400)
  __shared__ __align__(16) float ybuf[T5 + 64];    // [tile0-32, tile0+2336)
  const int tid = threadIdx.x;
  const int row = blockIdx.y;
  const int tile0 = blockIdx.x * T5;
  const float* xr = x + (size_t)row * L_;
  for (int i = tid; i < T5 + 160; i += 256) {
    int g = tile0 - 64 + i;
    xbuf[i] = (g >= 0 && g < L_) ? xr[g] : 0.0f;
  }
  __syncthreads();
  float accO[9];
#pragma unroll
  for (int r = 0; r < 9; ++r) accO[r] = 0.0f;
  const int rk0 = row * 4;
  k5_phase<65>(w0, xbuf, ybuf, accO, tile0, thr[rk0 + 0], keepAll[rk0 + 0], excN[rk0 + 0], excL + (size_t)(rk0 + 0) * 32);
  k5_phase<33>(w1, xbuf, ybuf, accO, tile0, thr[rk0 + 1], keepAll[rk0 + 1], excN[rk0 + 1], excL + (size_t)(rk0 + 1) * 32);
  k5_phase<17>(w2, xbuf, ybuf, accO, tile0, thr[rk0 + 2], keepAll[rk0 + 2], excN[rk0 + 2], excL + (size_t)(rk0 + 2) * 32);
  k5_phase< 9>(w3, xbuf, ybuf, accO, tile0, thr[rk0 + 3], keepAll[rk0 + 3], excN[rk0 + 3], excL + (size_t)(rk0 + 3) * 32);
  // stage to LDS, coalesced float4 store
  const int o0 = tid * 9;
#pragma unroll
  for (int r = 0; r < 9; ++r) xbuf[o0 + r] = accO[r];
  __syncthreads();
  float* orow = out + (size_t)row * L_;
  for (int i = tid; i < T5 / 4; i += 256) {
    int g4 = tile0 / 4 + i;
    if (g4 * 4 < L_) ((float4*)orow)[g4] = ((const float4*)xbuf)[i];
  }
}

// ---------------------------------------------------------------- host
extern "C" void kernel_launch(void* const* d_in, const int* in_sizes, int n_in,
                              void* d_out, int out_size, void* d_ws, size_t ws_size,
                              hipStream_t stream)
{
  (void)in_sizes; (void)n_in; (void)out_size; (void)ws_size;
  const float* x  = (const float*)d_in[0];
  const float* w0 = (const float*)d_in[1];
  const float* w1 = (const float*)d_in[2];
  const float* w2 = (const float*)d_in[3];
  const float* w3 = (const float*)d_in[4];
  float* out = (float*)d_out;

  u32* ghist  = (u32*)d_ws;                 // 256*8192 u32 (8 MiB)
  u32* ccount = ghist + 256 * NBINS;        // 256
  u32* bbin   = ccount + 256;
  u32* rrem   = bbin + 256;
  u32* thr    = rrem + 256;
  u32* kAll   = thr + 256;
  u32* excN   = kAll + 256;
  u32* excL   = excN + 256;                 // 256*32
  uint2* cand = (uint2*)(excL + 256 * 32);  // 256*CAPC uint2 (16 MiB) -> ~24.2 MiB ws

  hipMemsetAsync(ghist, 0, (size_t)(256 * NBINS + 256) * sizeof(u32), stream);

  dim3 g1(NCHUNK, 4, B_);
  k1_hist<<<g1, 256, 0, stream>>>(x, w0, w1, w2, w3, ghist);
  k2_findbin<<<256, 256, 0, stream>>>(ghist, bbin, rrem);
  k3_collect<<<g1, 256, 0, stream>>>(x, w0, w1, w2, w3, bbin, ccount, cand);
  k4_select<<<256, 256, 0, stream>>>(cand, ccount, bbin, rrem, thr, kAll, excN, excL);
  dim3 g5(NT5, B_);
  k5_final<<<g5, 256, 0, stream>>>(x, w0, w1, w2, w3, thr, kAll, excN, excL, out);
}

// Round 3
// 617.051 us; speedup vs baseline: 1.9248x; 1.9248x over previous
//
#include <hip/hip_runtime.h>
#include <stdint.h>

// SAN1d: 4x { y = conv_same(x,w); a = topk_abs(y,k); out += conv_same(a,w) }
// B=64 rows, L=262144, ks={65,33,17,9}, k=L//ks.
// Exact per-(row,kernel) threshold via 8192-bin histogram on |y| bits +
// candidate radix-select; y recomputed bit-identically (same fmaf chain) in
// K1/K3/K5 so the kept set is consistent across passes.
//
// R2 changes (profile-driven):
//  - k3: per-hit global atomicAdd(&ccount) WITH return was 768K serialized
//    atomics on 4 cache lines (718us, VALUBusy 10%). Now: LDS aggregation,
//    ONE global atomic per block, contiguous copy-out.
//  - all convs: weights hoisted to a fully-unrolled local array (SGPRs) so the
//    hot loop has no SMEM loads (SMEM is out-of-order -> forced lgkmcnt(0)
//    drains when mixed with ds_read).

#define B_ 64
#define L_ 262144
#define NBINS 8192      // |y| bits >> 18  (13 bits: exponent + 5 mantissa)
#define CAPC 8192       // candidate cap per (row,kernel); expected max ~3k
#define LCAP 1024       // per-block local candidate cap (expected ~270)
#define TSUB 2304       // 256 threads * 9 outputs
#define SUBS 8          // subtiles per K1/K3 block
#define NCHUNK 15       // ceil(L / (TSUB*SUBS))
#define T5 2304         // K5 tile
#define NT5 114         // ceil(L / T5)

typedef unsigned int u32;

__device__ const int d_K[4] = {4032, 7943, 15420, 29127};  // L_ // ks

// ---------------------------------------------------------------- K1 / K3 body
template<int KS, bool COLLECT>
__device__ __forceinline__ void conv_body(
    const float* __restrict__ x, const float* __restrict__ w,
    u32* __restrict__ ghist, const u32* __restrict__ bbin,
    u32* __restrict__ ccount, uint2* __restrict__ cand,
    float* xbuf, u32* hist, uint2* lcand, u32* lmeta)
{
  constexpr int PAD = KS / 2;
  constexpr int OFF = 32 - PAD;            // xbuf origin is base-32
  const int tid = threadIdx.x;
  const int kk  = blockIdx.y;
  const int row = blockIdx.z;
  const int rk  = row * 4 + kk;
  const float* xr = x + (size_t)row * L_;

  // weights -> registers/SGPRs once (no SMEM loads in the hot loop)
  float wreg[KS];
#pragma unroll
  for (int j = 0; j < KS; ++j) wreg[j] = w[j];

  u32 target = 0;
  if (COLLECT) {
    target = bbin[rk];
    if (tid == 0) lmeta[0] = 0u;           // local candidate count
  } else {
    for (int i = tid; i < NBINS; i += 256) hist[i] = 0u;
  }
  __syncthreads();

  for (int it = 0; it < SUBS; ++it) {
    const int base = (blockIdx.x * SUBS + it) * TSUB;
    if (base >= L_) break;                 // uniform across block
    for (int i = tid; i < TSUB + 64; i += 256) {
      int g = base - 32 + i;
      xbuf[i] = (g >= 0 && g < L_) ? xr[g] : 0.0f;   // SAME zero-pad as real taps
    }
    __syncthreads();

    float acc[9];
#pragma unroll
    for (int r = 0; r < 9; ++r) acc[r] = 0.0f;
    const int q0 = tid * 9;                // lane stride 9 (coprime 32) -> bank-clean
#pragma unroll
    for (int p = 0; p < KS + 8; ++p) {     // sliding window: p = r + j
      float xv = xbuf[q0 + OFF + p];
#pragma unroll
      for (int r = 0; r < 9; ++r) {
        const int j = p - r;
        if (j >= 0 && j < KS) acc[r] = fmaf(xv, wreg[j], acc[r]);  // j-ascending chain
      }
    }
#pragma unroll
    for (int r = 0; r < 9; ++r) {
      int g = base + q0 + r;
      if (g < L_) {
        u32 ab = __float_as_uint(acc[r]) & 0x7fffffffu;
        if (!COLLECT) {
          atomicAdd(&hist[ab >> 18], 1u);
        } else if ((ab >> 18) == target) {
          u32 slot = atomicAdd(&lmeta[0], 1u);       // LDS atomic (cheap)
          if (slot < LCAP) lcand[slot] = make_uint2(ab, (u32)g);
        }
      }
    }
    __syncthreads();
  }

  if (!COLLECT) {
    u32* gh = ghist + (size_t)rk * NBINS;
    for (int i = tid; i < NBINS; i += 256) {
      u32 c = hist[i];
      if (c) atomicAdd(&gh[i], c);         // skip-zero merge (device-scope)
    }
  } else {
    // flush: ONE global atomic per block, then contiguous copy-out
    if (tid == 0) {
      u32 m = lmeta[0]; if (m > LCAP) m = LCAP;
      lmeta[1] = m;
      lmeta[2] = atomicAdd(&ccount[rk], m);
    }
    __syncthreads();
    const u32 m = lmeta[1], bse = lmeta[2];
    uint2* cd = cand + (size_t)rk * CAPC;
    for (u32 i = tid; i < m; i += 256)
      if (bse + i < CAPC) cd[bse + i] = lcand[i];
  }
}

__global__ __launch_bounds__(256) void k1_hist(
    const float* __restrict__ x, const float* __restrict__ w0,
    const float* __restrict__ w1, const float* __restrict__ w2,
    const float* __restrict__ w3, u32* __restrict__ ghist)
{
  __shared__ float xbuf[TSUB + 64];
  __shared__ u32 hist[NBINS];              // ~42 KB static LDS
  switch (blockIdx.y) {
    case 0:  conv_body<65, false>(x, w0, ghist, nullptr, nullptr, nullptr, xbuf, hist, nullptr, nullptr); break;
    case 1:  conv_body<33, false>(x, w1, ghist, nullptr, nullptr, nullptr, xbuf, hist, nullptr, nullptr); break;
    case 2:  conv_body<17, false>(x, w2, ghist, nullptr, nullptr, nullptr, xbuf, hist, nullptr, nullptr); break;
    default: conv_body< 9, false>(x, w3, ghist, nullptr, nullptr, nullptr, xbuf, hist, nullptr, nullptr); break;
  }
}

__global__ __launch_bounds__(256) void k3_collect(
    const float* __restrict__ x, const float* __restrict__ w0,
    const float* __restrict__ w1, const float* __restrict__ w2,
    const float* __restrict__ w3, const u32* __restrict__ bbin,
    u32* __restrict__ ccount, uint2* __restrict__ cand)
{
  __shared__ float xbuf[TSUB + 64];
  __shared__ uint2 lcand[LCAP];            // 8 KB
  __shared__ u32 lmeta[3];
  switch (blockIdx.y) {
    case 0:  conv_body<65, true>(x, w0, nullptr, bbin, ccount, cand, xbuf, nullptr, lcand, lmeta); break;
    case 1:  conv_body<33, true>(x, w1, nullptr, bbin, ccount, cand, xbuf, nullptr, lcand, lmeta); break;
    case 2:  conv_body<17, true>(x, w2, nullptr, bbin, ccount, cand, xbuf, nullptr, lcand, lmeta); break;
    default: conv_body< 9, true>(x, w3, nullptr, bbin, ccount, cand, xbuf, nullptr, lcand, lmeta); break;
  }
}

// ---------------------------------------------------------------- K2: bin find
__global__ __launch_bounds__(256) void k2_findbin(
    const u32* __restrict__ ghist, u32* __restrict__ bbin, u32* __restrict__ rrem)
{
  __shared__ u32 h[NBINS];
  __shared__ u32 ssum[256];
  const int rk = blockIdx.x;
  const u32 k = (u32)d_K[rk & 3];
  const u32* gh = ghist + (size_t)rk * NBINS;
  for (int i = threadIdx.x; i < NBINS; i += 256) h[i] = gh[i];
  __syncthreads();
  u32 s = 0;
  for (int i = 0; i < 32; ++i) s += h[threadIdx.x * 32 + i];
  ssum[threadIdx.x] = s;
  __syncthreads();
  if (threadIdx.x == 0) {
    u32 cum = 0; int b = 0;
    for (int t = 255; t >= 0; --t) {       // walk bins from the top (largest |y|)
      if (cum + ssum[t] >= k) {
        for (int i = t * 32 + 31; i >= t * 32; --i) {
          if (cum + h[i] >= k) { b = i; break; }
          cum += h[i];
        }
        break;
      }
      cum += ssum[t];
    }
    bbin[rk] = (u32)b;
    rrem[rk] = k - cum;                    // 1-based rank inside bin b
  }
}

// ---------------------------------------------------------------- K4: select
__global__ __launch_bounds__(256) void k4_select(
    const uint2* __restrict__ cand, const u32* __restrict__ ccount,
    const u32* __restrict__ bbinA, const u32* __restrict__ rremA,
    u32* __restrict__ thr, u32* __restrict__ keepAll,
    u32* __restrict__ excN, u32* __restrict__ excL)
{
  __shared__ u32 cab[CAPC];
  __shared__ u32 h64[64];
  __shared__ u32 sh[3];
  __shared__ u32 lidx[64];
  __shared__ u32 lcnt;
  const int rk = blockIdx.x;
  int n = (int)min(ccount[rk], (u32)CAPC);
  u32 r = rremA[rk];
  if (r > (u32)n) r = (u32)n;              // overflow fallback (statistically never)
  const uint2* cd = cand + (size_t)rk * CAPC;
  for (int i = threadIdx.x; i < n; i += 256) cab[i] = cd[i].x & 0x3ffffu;

  u32 sel = 0;
  for (int round = 0; round < 3; ++round) {  // 3 x 6-bit MSD radix select
    const int shift = 12 - 6 * round;
    const u32 himask = (round == 0) ? 0u : ((0x3ffffu << (shift + 6)) & 0x3ffffu);
    if (threadIdx.x < 64) h64[threadIdx.x] = 0u;
    __syncthreads();
    for (int i = threadIdx.x; i < n; i += 256) {
      u32 v = cab[i];
      if ((v & himask) == (sel & himask)) atomicAdd(&h64[(v >> shift) & 63u], 1u);
    }
    __syncthreads();
    if (threadIdx.x == 0) {
      u32 cum = 0; int d = 0;
      for (int dd = 63; dd >= 0; --dd) {
        if (cum + h64[dd] >= r) { d = dd; break; }
        cum += h64[dd];
      }
      sh[0] = (u32)d;
      sh[1] = r - cum;
      sh[2] = h64[d];
    }
    __syncthreads();
    sel |= sh[0] << shift;
    r = sh[1];
  }
  const u32 dup = sh[2];                   // multiplicity of the threshold value
  const u32 m = r;                         // how many of the tied values to keep
  if (threadIdx.x == 0) thr[rk] = (bbinA[rk] << 18) | sel;

  if (m >= dup) {
    if (threadIdx.x == 0) { keepAll[rk] = 1u; excN[rk] = 0u; }
    return;
  }
  if (threadIdx.x == 0) lcnt = 0u;
  __syncthreads();
  for (int i = threadIdx.x; i < n; i += 256) {
    if (cab[i] == sel) {
      u32 s2 = atomicAdd(&lcnt, 1u);
      if (s2 < 64) lidx[s2] = cd[i].y;
    }
  }
  __syncthreads();
  if (threadIdx.x == 0) {
    int c = (int)min(lcnt, 64u);
    for (int i = 1; i < c; ++i) {          // sort ascending index (top_k stable tie-break)
      u32 v = lidx[i]; int j = i - 1;
      while (j >= 0 && lidx[j] > v) { lidx[j + 1] = lidx[j]; --j; }
      lidx[j + 1] = v;
    }
    u32 mm = min(m, 32u);
    keepAll[rk] = 0u; excN[rk] = mm;
    for (u32 i = 0; i < mm; ++i) excL[(size_t)rk * 32 + i] = lidx[i];
  }
}

// ---------------------------------------------------------------- K5: final
template<int KS>
__device__ __forceinline__ void k5_phase(
    const float* __restrict__ w, const float* xbuf, float* ybuf, float* accO,
    int tile0, u32 t_ab, u32 kAll, u32 en, const u32* __restrict__ excLrk)
{
  constexpr int PAD = KS / 2;
  constexpr int OFF2 = 32 - PAD;
  const int tid = threadIdx.x;

  float wreg[KS];
#pragma unroll
  for (int j = 0; j < KS; ++j) wreg[j] = w[j];

  // --- recompute y on [tile0-32, tile0+T5+32), mask by threshold, store to ybuf
  const int q0 = tid * 10;
  if (q0 < T5 + 64) {
    float a[10];
#pragma unroll
    for (int r = 0; r < 10; ++r) a[r] = 0.0f;
#pragma unroll
    for (int p = 0; p < KS + 9; ++p) {
      float xv = xbuf[q0 + OFF2 + p];
#pragma unroll
      for (int r = 0; r < 10; ++r) {
        const int j = p - r;
        if (j >= 0 && j < KS) a[r] = fmaf(xv, wreg[j], a[r]);  // identical chain to K1/K3
      }
    }
#pragma unroll
    for (int r = 0; r < 10; ++r) {
      int q = q0 + r;
      if (q < T5 + 64) {
        int g = tile0 - 32 + q;
        float av = 0.0f;
        if (g >= 0 && g < L_) {
          float yv = a[r];
          u32 ab = __float_as_uint(yv) & 0x7fffffffu;
          bool keep = ab > t_ab;
          if (ab == t_ab) {                // threshold ties: exact top_k semantics
            if (kAll) keep = true;
            else {
              for (u32 e = 0; e < en; ++e)
                if (excLrk[e] == (u32)g) { keep = true; break; }
            }
          }
          av = keep ? yv : 0.0f;
        }
        ybuf[q] = av;
      }
    }
  }
  __syncthreads();
  // --- second conv from ybuf into accO
  {
    const int o0 = tid * 9;
#pragma unroll
    for (int p = 0; p < KS + 8; ++p) {
      float yv = ybuf[o0 + OFF2 + p];
#pragma unroll
      for (int r = 0; r < 9; ++r) {
        const int j = p - r;
        if (j >= 0 && j < KS) accO[r] = fmaf(yv, wreg[j], accO[r]);
      }
    }
  }
  __syncthreads();
}

__global__ __launch_bounds__(256) void k5_final(
    const float* __restrict__ x, const float* __restrict__ w0,
    const float* __restrict__ w1, const float* __restrict__ w2,
    const float* __restrict__ w3, const u32* __restrict__ thr,
    const u32* __restrict__ keepAll, const u32* __restrict__ excN,
    const u32* __restrict__ excL, float* __restrict__ out)
{
  __shared__ __align__(16) float xbuf[T5 + 160];   // [tile0-64, tile0+2400)
  __shared__ __align__(16) float ybuf[T5 + 64];    // [tile0-32, tile0+2336)
  const int tid = threadIdx.x;
  const int row = blockIdx.y;
  const int tile0 = blockIdx.x * T5;
  const float* xr = x + (size_t)row * L_;
  for (int i = tid; i < T5 + 160; i += 256) {
    int g = tile0 - 64 + i;
    xbuf[i] = (g >= 0 && g < L_) ? xr[g] : 0.0f;
  }
  __syncthreads();
  float accO[9];
#pragma unroll
  for (int r = 0; r < 9; ++r) accO[r] = 0.0f;
  const int rk0 = row * 4;
  k5_phase<65>(w0, xbuf, ybuf, accO, tile0, thr[rk0 + 0], keepAll[rk0 + 0], excN[rk0 + 0], excL + (size_t)(rk0 + 0) * 32);
  k5_phase<33>(w1, xbuf, ybuf, accO, tile0, thr[rk0 + 1], keepAll[rk0 + 1], excN[rk0 + 1], excL + (size_t)(rk0 + 1) * 32);
  k5_phase<17>(w2, xbuf, ybuf, accO, tile0, thr[rk0 + 2], keepAll[rk0 + 2], excN[rk0 + 2], excL + (size_t)(rk0 + 2) * 32);
  k5_phase< 9>(w3, xbuf, ybuf, accO, tile0, thr[rk0 + 3], keepAll[rk0 + 3], excN[rk0 + 3], excL + (size_t)(rk0 + 3) * 32);
  // stage to LDS, coalesced float4 store
  const int o0 = tid * 9;
#pragma unroll
  for (int r = 0; r < 9; ++r) xbuf[o0 + r] = accO[r];
  __syncthreads();
  float* orow = out + (size_t)row * L_;
  for (int i = tid; i < T5 / 4; i += 256) {
    int g4 = tile0 / 4 + i;
    if (g4 * 4 < L_) ((float4*)orow)[g4] = ((const float4*)xbuf)[i];
  }
}

// ---------------------------------------------------------------- host
extern "C" void kernel_launch(void* const* d_in, const int* in_sizes, int n_in,
                              void* d_out, int out_size, void* d_ws, size_t ws_size,
                              hipStream_t stream)
{
  (void)in_sizes; (void)n_in; (void)out_size; (void)ws_size;
  const float* x  = (const float*)d_in[0];
  const float* w0 = (const float*)d_in[1];
  const float* w1 = (const float*)d_in[2];
  const float* w2 = (const float*)d_in[3];
  const float* w3 = (const float*)d_in[4];
  float* out = (float*)d_out;

  u32* ghist  = (u32*)d_ws;                 // 256*8192 u32 (8 MiB)
  u32* ccount = ghist + 256 * NBINS;        // 256
  u32* bbin   = ccount + 256;
  u32* rrem   = bbin + 256;
  u32* thr    = rrem + 256;
  u32* kAll   = thr + 256;
  u32* excN   = kAll + 256;
  u32* excL   = excN + 256;                 // 256*32
  uint2* cand = (uint2*)(excL + 256 * 32);  // 256*CAPC uint2 (16 MiB) -> ~24.2 MiB ws

  hipMemsetAsync(ghist, 0, (size_t)(256 * NBINS + 256) * sizeof(u32), stream);

  dim3 g1(NCHUNK, 4, B_);
  k1_hist<<<g1, 256, 0, stream>>>(x, w0, w1, w2, w3, ghist);
  k2_findbin<<<256, 256, 0, stream>>>(ghist, bbin, rrem);
  k3_collect<<<g1, 256, 0, stream>>>(x, w0, w1, w2, w3, bbin, ccount, cand);
  k4_select<<<256, 256, 0, stream>>>(cand, ccount, bbin, rrem, thr, kAll, excN, excL);
  dim3 g5(NT5, B_);
  k5_final<<<g5, 256, 0, stream>>>(x, w0, w1, w2, w3, thr, kAll, excN, excL, out);
}

// Round 6
// 526.010 us; speedup vs baseline: 2.2579x; 1.1731x over previous
//
#include <hip/hip_runtime.h>
#include <stdint.h>

// SAN1d: 4x { y = conv_same(x,w); a = topk_abs(y,k); out += conv_same(a,w) }
// B=64 rows, L=262144, ks={65,33,17,9}, k=L//ks.
//
// R4 structure (resubmitted R6; two acquisition timeouts, change-set still
// unmeasured): y computed ONCE in k1 (same fmaf chain as R2/R3 -> identical
// bits/absmax) and stored to ws; k3 is a pure scan of stored y; k5 reads y,
// masks, and does only the second conv. k1's histogram packed to u16 pairs
// (LDS 42.5->25.9KB -> 6 blocks/CU), all staging vectorized float4.
// Launcher adapts group size (4/2/1) to ws_size.

#define B_ 64
#define L_ 262144
#define NBINS 8192      // |y| bits >> 18  (13 bits: exponent + 5 mantissa)
#define CAPC 8192       // candidate cap per (row,kernel); expected max ~2k
#define LCAP 1024       // per-block local candidate cap
#define TSUB 2304       // 256 threads * 9 outputs
#define SUBS 8          // subtiles per K1 block
#define NCHUNK 15       // ceil(L / (TSUB*SUBS))
#define T5 2304         // K5 tile
#define NT5 114         // ceil(L / T5)
#define NSCAN 16        // k3 scan blocks per (row,kernel); L/NSCAN = 16384

typedef unsigned int u32;

__device__ const int d_K[4] = {4032, 7943, 15420, 29127};  // L_ // ks

// ---------------------------------------------------------------- K1 body
template<int KS>
__device__ __forceinline__ void k1_body(
    const float* __restrict__ xr, const float* __restrict__ w,
    float* __restrict__ yrow, u32* __restrict__ gh,
    float* xbuf, u32* h32)
{
  constexpr int PAD = KS / 2;
  constexpr int OFF = 32 - PAD;            // xbuf origin is base-32
  const int tid = threadIdx.x;

  float wreg[KS];
#pragma unroll
  for (int j = 0; j < KS; ++j) wreg[j] = w[j];

  for (int i = tid; i < NBINS / 2; i += 256) h32[i] = 0u;
  __syncthreads();

  for (int it = 0; it < SUBS; ++it) {
    const int base = (blockIdx.x * SUBS + it) * TSUB;
    if (base >= L_) break;                 // uniform across block
    // ---- stage x [base-32, base+TSUB+32)
    const bool interior = (base >= 32) && (base + TSUB + 32 <= L_);
    if (interior) {
      const float4* src = (const float4*)(xr + base - 32);
      for (int i = tid; i < (TSUB + 64) / 4; i += 256)
        ((float4*)xbuf)[i] = src[i];
    } else {
      for (int i = tid; i < TSUB + 64; i += 256) {
        int g = base - 32 + i;
        xbuf[i] = (g >= 0 && g < L_) ? xr[g] : 0.0f;  // SAME zero-pad as real taps
      }
    }
    __syncthreads();

    // ---- conv: 9 outputs/thread, j-ascending fmaf chain (bit-stable)
    float acc[9];
#pragma unroll
    for (int r = 0; r < 9; ++r) acc[r] = 0.0f;
    const int q0 = tid * 9;                // stride 9 (coprime 32) -> bank-clean
#pragma unroll
    for (int p = 0; p < KS + 8; ++p) {     // sliding window: p = r + j
      float xv = xbuf[q0 + OFF + p];
#pragma unroll
      for (int r = 0; r < 9; ++r) {
        const int j = p - r;
        if (j >= 0 && j < KS) acc[r] = fmaf(xv, wreg[j], acc[r]);
      }
    }
    // ---- histogram (packed u16 pairs; per-block total 18432 -> no overflow)
#pragma unroll
    for (int r = 0; r < 9; ++r) {
      int g = base + q0 + r;
      if (g < L_) {
        u32 ab = __float_as_uint(acc[r]) & 0x7fffffffu;
        u32 bin = ab >> 18;
        atomicAdd(&h32[bin >> 1], 1u << (16 * (bin & 1)));
      }
    }
    __syncthreads();                       // conv reads of xbuf done
    // ---- stage y into xbuf, coalesced float4 store
#pragma unroll
    for (int r = 0; r < 9; ++r) xbuf[q0 + r] = acc[r];
    __syncthreads();
    const int n4 = (min(TSUB, L_ - base)) / 4;   // multiples of 4 -> exact
    float4* dst = (float4*)(yrow + base);
    for (int i = tid; i < n4; i += 256) dst[i] = ((const float4*)xbuf)[i];
    __syncthreads();                       // xbuf reused by next subtile
  }

  // ---- merge histogram
  for (int i = tid; i < NBINS / 2; i += 256) {
    u32 v = h32[i];
    u32 lo = v & 0xffffu, hi = v >> 16;
    if (lo) atomicAdd(&gh[2 * i], lo);
    if (hi) atomicAdd(&gh[2 * i + 1], hi);
  }
}

__global__ __launch_bounds__(256) void k1_hist(
    const float* __restrict__ x, const float* __restrict__ w0,
    const float* __restrict__ w1, const float* __restrict__ w2,
    const float* __restrict__ w3, float* __restrict__ y,
    u32* __restrict__ ghist, int kk0, int ng)
{
  __shared__ __align__(16) float xbuf[TSUB + 64];
  __shared__ u32 h32[NBINS / 2];           // 16 KB packed u16 hist
  const int kg = blockIdx.y;
  const int row = blockIdx.z;
  const int rkl = row * ng + kg;
  const int kk = kk0 + kg;
  const float* xr = x + (size_t)row * L_;
  float* yrow = y + (size_t)rkl * L_;
  u32* gh = ghist + (size_t)rkl * NBINS;
  switch (kk) {
    case 0:  k1_body<65>(xr, w0, yrow, gh, xbuf, h32); break;
    case 1:  k1_body<33>(xr, w1, yrow, gh, xbuf, h32); break;
    case 2:  k1_body<17>(xr, w2, yrow, gh, xbuf, h32); break;
    default: k1_body< 9>(xr, w3, yrow, gh, xbuf, h32); break;
  }
}

// ---------------------------------------------------------------- K2: bin find
__global__ __launch_bounds__(256) void k2_findbin(
    const u32* __restrict__ ghist, u32* __restrict__ bbin, u32* __restrict__ rrem,
    int kk0, int ng)
{
  __shared__ u32 h[NBINS];
  __shared__ u32 ssum[256];
  const int rkl = blockIdx.x;
  const u32 k = (u32)d_K[kk0 + (rkl % ng)];
  const u32* gh = ghist + (size_t)rkl * NBINS;
  for (int i = threadIdx.x; i < NBINS; i += 256) h[i] = gh[i];
  __syncthreads();
  u32 s = 0;
  for (int i = 0; i < 32; ++i) s += h[threadIdx.x * 32 + i];
  ssum[threadIdx.x] = s;
  __syncthreads();
  if (threadIdx.x == 0) {
    u32 cum = 0; int b = 0;
    for (int t = 255; t >= 0; --t) {       // walk from the top (largest |y|)
      if (cum + ssum[t] >= k) {
        for (int i = t * 32 + 31; i >= t * 32; --i) {
          if (cum + h[i] >= k) { b = i; break; }
          cum += h[i];
        }
        break;
      }
      cum += ssum[t];
    }
    bbin[rkl] = (u32)b;
    rrem[rkl] = k - cum;                   // 1-based rank inside bin b
  }
}

// ---------------------------------------------------------------- K3: scan y
__global__ __launch_bounds__(256) void k3_scan(
    const float* __restrict__ y, const u32* __restrict__ bbin,
    u32* __restrict__ ccount, uint2* __restrict__ cand, int ng)
{
  __shared__ uint2 lcand[LCAP];
  __shared__ u32 lmeta[3];
  const int tid = threadIdx.x;
  const int rkl = blockIdx.z * ng + blockIdx.y;
  const u32 target = bbin[rkl];
  if (tid == 0) lmeta[0] = 0u;
  __syncthreads();
  const float* yr = y + (size_t)rkl * L_;
  const int c0 = blockIdx.x * (L_ / NSCAN);
  const float4* src = (const float4*)(yr + c0);
  for (int i = tid; i < (L_ / NSCAN) / 4; i += 256) {
    float4 v = src[i];
    const float* vf = (const float*)&v;
#pragma unroll
    for (int c = 0; c < 4; ++c) {
      u32 ab = __float_as_uint(vf[c]) & 0x7fffffffu;
      if ((ab >> 18) == target) {
        u32 slot = atomicAdd(&lmeta[0], 1u);
        if (slot < LCAP) lcand[slot] = make_uint2(ab, (u32)(c0 + 4 * i + c));
      }
    }
  }
  __syncthreads();
  if (tid == 0) {
    u32 m = lmeta[0]; if (m > LCAP) m = LCAP;
    lmeta[1] = m;
    lmeta[2] = atomicAdd(&ccount[rkl], m);
  }
  __syncthreads();
  const u32 m = lmeta[1], bse = lmeta[2];
  uint2* cd = cand + (size_t)rkl * CAPC;
  for (u32 i = tid; i < m; i += 256)
    if (bse + i < CAPC) cd[bse + i] = lcand[i];
}

// ---------------------------------------------------------------- K4: select
__global__ __launch_bounds__(256) void k4_select(
    const uint2* __restrict__ cand, const u32* __restrict__ ccount,
    const u32* __restrict__ bbinA, const u32* __restrict__ rremA,
    u32* __restrict__ thr, u32* __restrict__ keepAll,
    u32* __restrict__ excN, u32* __restrict__ excL)
{
  __shared__ u32 cab[CAPC];
  __shared__ u32 h64[64];
  __shared__ u32 sh[3];
  __shared__ u32 lidx[64];
  __shared__ u32 lcnt;
  const int rkl = blockIdx.x;
  int n = (int)min(ccount[rkl], (u32)CAPC);
  u32 r = rremA[rkl];
  if (r > (u32)n) r = (u32)n;              // overflow fallback (statistically never)
  const uint2* cd = cand + (size_t)rkl * CAPC;
  for (int i = threadIdx.x; i < n; i += 256) cab[i] = cd[i].x & 0x3ffffu;

  u32 sel = 0;
  for (int round = 0; round < 3; ++round) {  // 3 x 6-bit MSD radix select
    const int shift = 12 - 6 * round;
    const u32 himask = (round == 0) ? 0u : ((0x3ffffu << (shift + 6)) & 0x3ffffu);
    if (threadIdx.x < 64) h64[threadIdx.x] = 0u;
    __syncthreads();
    for (int i = threadIdx.x; i < n; i += 256) {
      u32 v = cab[i];
      if ((v & himask) == (sel & himask)) atomicAdd(&h64[(v >> shift) & 63u], 1u);
    }
    __syncthreads();
    if (threadIdx.x == 0) {
      u32 cum = 0; int d = 0;
      for (int dd = 63; dd >= 0; --dd) {
        if (cum + h64[dd] >= r) { d = dd; break; }
        cum += h64[dd];
      }
      sh[0] = (u32)d;
      sh[1] = r - cum;
      sh[2] = h64[d];
    }
    __syncthreads();
    sel |= sh[0] << shift;
    r = sh[1];
  }
  const u32 dup = sh[2];                   // multiplicity of threshold value
  const u32 m = r;                         // how many tied values to keep
  if (threadIdx.x == 0) thr[rkl] = (bbinA[rkl] << 18) | sel;

  if (m >= dup) {
    if (threadIdx.x == 0) { keepAll[rkl] = 1u; excN[rkl] = 0u; }
    return;
  }
  if (threadIdx.x == 0) lcnt = 0u;
  __syncthreads();
  for (int i = threadIdx.x; i < n; i += 256) {
    if (cab[i] == sel) {
      u32 s2 = atomicAdd(&lcnt, 1u);
      if (s2 < 64) lidx[s2] = cd[i].y;
    }
  }
  __syncthreads();
  if (threadIdx.x == 0) {
    int c = (int)min(lcnt, 64u);
    for (int i = 1; i < c; ++i) {          // sort ascending index (top_k tie-break)
      u32 v = lidx[i]; int j = i - 1;
      while (j >= 0 && lidx[j] > v) { lidx[j + 1] = lidx[j]; --j; }
      lidx[j + 1] = v;
    }
    u32 mm = min(m, 32u);
    keepAll[rkl] = 0u; excN[rkl] = mm;
    for (u32 i = 0; i < mm; ++i) excL[(size_t)rkl * 32 + i] = lidx[i];
  }
}

// ---------------------------------------------------------------- K5: final
__device__ __forceinline__ float k5_mask(float yv, int g, u32 t_ab, u32 ka,
                                         u32 en, const u32* __restrict__ excp)
{
  u32 ab = __float_as_uint(yv) & 0x7fffffffu;
  bool keep = ab > t_ab;
  if (ab == t_ab) {
    if (ka) keep = true;
    else {
      for (u32 e = 0; e < en; ++e)
        if (excp[e] == (u32)g) { keep = true; break; }
    }
  }
  return keep ? yv : 0.0f;
}

template<int KS>
__device__ __forceinline__ void k5_conv(
    const float* __restrict__ w, const float* abuf, float* accO)
{
  constexpr int PAD = KS / 2;
  constexpr int OFF2 = 32 - PAD;
  float wreg[KS];
#pragma unroll
  for (int j = 0; j < KS; ++j) wreg[j] = w[j];
  const int o0 = threadIdx.x * 9;
#pragma unroll
  for (int p = 0; p < KS + 8; ++p) {
    float av = abuf[o0 + OFF2 + p];
#pragma unroll
    for (int r = 0; r < 9; ++r) {
      const int j = p - r;
      if (j >= 0 && j < KS) accO[r] = fmaf(av, wreg[j], accO[r]);
    }
  }
}

__global__ __launch_bounds__(256) void k5_final(
    const float* __restrict__ y, const float* __restrict__ w0,
    const float* __restrict__ w1, const float* __restrict__ w2,
    const float* __restrict__ w3, const u32* __restrict__ thr,
    const u32* __restrict__ keepAll, const u32* __restrict__ excN,
    const u32* __restrict__ excL, float* __restrict__ out,
    int kk0, int ng)
{
  __shared__ __align__(16) float abuf[T5 + 64];
  const int tid = threadIdx.x;
  const int row = blockIdx.y;
  const int tile0 = blockIdx.x * T5;
  float accO[9];
#pragma unroll
  for (int r = 0; r < 9; ++r) accO[r] = 0.0f;

  for (int kg = 0; kg < ng; ++kg) {
    const int rkl = row * ng + kg;
    const int kk = kk0 + kg;
    const u32 t_ab = thr[rkl], ka = keepAll[rkl], en = excN[rkl];
    const u32* excp = excL + (size_t)rkl * 32;
    const float* yr = y + (size_t)rkl * L_;
    // stage masked activations on [tile0-32, tile0+T5+32)
    const bool interior = (tile0 >= 32) && (tile0 + T5 + 32 <= L_);
    if (interior) {
      const float4* src = (const float4*)(yr + tile0 - 32);
      for (int i = tid; i < (T5 + 64) / 4; i += 256) {
        float4 v = src[i];
        float* vf = (float*)&v;
#pragma unroll
        for (int c = 0; c < 4; ++c)
          vf[c] = k5_mask(vf[c], tile0 - 32 + 4 * i + c, t_ab, ka, en, excp);
        ((float4*)abuf)[i] = v;
      }
    } else {
      for (int i = tid; i < T5 + 64; i += 256) {
        int g = tile0 - 32 + i;
        float av = 0.0f;
        if (g >= 0 && g < L_) av = k5_mask(yr[g], g, t_ab, ka, en, excp);
        abuf[i] = av;
      }
    }
    __syncthreads();
    switch (kk) {
      case 0:  k5_conv<65>(w0, abuf, accO); break;
      case 1:  k5_conv<33>(w1, abuf, accO); break;
      case 2:  k5_conv<17>(w2, abuf, accO); break;
      default: k5_conv< 9>(w3, abuf, accO); break;
    }
    __syncthreads();                       // abuf reused by next kg
  }

  // stage result, coalesced float4 store (+accumulate for later groups)
  const int o0 = tid * 9;
#pragma unroll
  for (int r = 0; r < 9; ++r) abuf[o0 + r] = accO[r];
  __syncthreads();
  float* orow = out + (size_t)row * L_ + tile0;
  const int n4 = (min(T5, L_ - tile0)) / 4;
  if (kk0 == 0) {
    for (int i = tid; i < n4; i += 256)
      ((float4*)orow)[i] = ((const float4*)abuf)[i];
  } else {
    for (int i = tid; i < n4; i += 256) {
      float4 prev = ((const float4*)orow)[i];
      float4 add = ((const float4*)abuf)[i];
      prev.x += add.x; prev.y += add.y; prev.z += add.z; prev.w += add.w;
      ((float4*)orow)[i] = prev;
    }
  }
}

// ---------------------------------------------------------------- host
extern "C" void kernel_launch(void* const* d_in, const int* in_sizes, int n_in,
                              void* d_out, int out_size, void* d_ws, size_t ws_size,
                              hipStream_t stream)
{
  (void)in_sizes; (void)n_in; (void)out_size;
  const float* x  = (const float*)d_in[0];
  const float* w0 = (const float*)d_in[1];
  const float* w1 = (const float*)d_in[2];
  const float* w2 = (const float*)d_in[3];
  const float* w3 = (const float*)d_in[4];
  float* out = (float*)d_out;

  // per-group ws need: y + ghist + ccount + bbin/rrem/thr/kAll/excN + excL + cand
  auto need = [](int ng) -> size_t {
    return (size_t)ng * 64 * ((size_t)L_ * 4 + NBINS * 4 + 4 * 6 + 32 * 4 + CAPC * 8);
  };
  int ng = 1;
  if (ws_size >= need(4)) ng = 4;
  else if (ws_size >= need(2)) ng = 2;

  const size_t NRK = (size_t)64 * ng;
  float* y     = (float*)d_ws;
  u32* ghist   = (u32*)(y + NRK * L_);
  u32* ccount  = ghist + NRK * NBINS;
  u32* bbin    = ccount + NRK;
  u32* rrem    = bbin + NRK;
  u32* thr     = rrem + NRK;
  u32* kAll    = thr + NRK;
  u32* excN    = kAll + NRK;
  u32* excL    = excN + NRK;               // NRK*32
  uint2* cand  = (uint2*)(excL + NRK * 32);

  for (int kk0 = 0; kk0 < 4; kk0 += ng) {
    hipMemsetAsync(ghist, 0, (NRK * NBINS + NRK) * sizeof(u32), stream);  // ghist+ccount
    dim3 g1(NCHUNK, ng, B_);
    k1_hist<<<g1, 256, 0, stream>>>(x, w0, w1, w2, w3, y, ghist, kk0, ng);
    k2_findbin<<<(int)NRK, 256, 0, stream>>>(ghist, bbin, rrem, kk0, ng);
    dim3 g3(NSCAN, ng, B_);
    k3_scan<<<g3, 256, 0, stream>>>(y, bbin, ccount, cand, ng);
    k4_select<<<(int)NRK, 256, 0, stream>>>(cand, ccount, bbin, rrem, thr, kAll, excN, excL);
    dim3 g5(NT5, B_);
    k5_final<<<g5, 256, 0, stream>>>(y, w0, w1, w2, w3, thr, kAll, excN, excL, out, kk0, ng);
  }
}

// Round 7
// 502.827 us; speedup vs baseline: 2.3620x; 1.0461x over previous
//
#include <hip/hip_runtime.h>
#include <stdint.h>

// SAN1d: 4x { y = conv_same(x,w); a = topk_abs(y,k); out += conv_same(a,w) }
// B=64 rows, L=262144, ks={65,33,17,9}, k=L//ks.
//
// R6 (profile-driven): k1 was 2x169us at VALUBusy 37% / HBM 15% -> stall-bound
// (4 barriers/subtile, vmcnt drains right after stores, reg-roundtrip staging).
// Now: double-buffered LDS + global_load_lds(16B) prefetch issued before conv,
// ONE barrier per subtile, y stored directly from acc regs (bit-identical).
// k5 writes out directly from regs. k2 folded into k3 (per-block bin-find).

#define B_ 64
#define L_ 262144
#define NBINS 8192      // |y| bits >> 18  (13 bits: exponent + 5 mantissa)
#define CAPC 8192       // candidate cap per (row,kernel); expected max ~2k
#define LCAP 1024       // per-block local candidate cap
#define TSUB 2304       // 256 threads * 9 outputs
#define SUBS 8          // subtiles per K1 block
#define NCHUNK 15       // ceil(L / (TSUB*SUBS))
#define XSTG 2560       // staged tile incl. halo+gload padding (floats)
#define T5 2304         // K5 tile
#define NT5 114         // ceil(L / T5)
#define NSCAN 16        // k3 scan blocks per (row,kernel); L/NSCAN = 16384

typedef unsigned int u32;

__device__ const int d_K[4] = {4032, 7943, 15420, 29127};  // L_ // ks

// ---------------------------------------------------------------- K1 staging
// Interior: async global->LDS, 16B/lane, wave-uniform LDS base (+lane*16 by HW).
// Pad region [2368,2560) may hold garbage row data; conv never reads it.
__device__ __forceinline__ void k1_stage(const float* __restrict__ xr, int base,
                                         float* dst, int tid)
{
  const bool interior = (base >= 32) && (base - 32 + XSTG <= L_);
  if (interior) {
    const float* g0 = xr + (base - 32);
    const int wv = tid >> 6, lane = tid & 63;
#pragma unroll
    for (int r = 0; r < 3; ++r) {
      const int off = (r * 4 + wv) * 256;          // floats; wave-uniform
      if (off < XSTG) {
        __builtin_amdgcn_global_load_lds(
            (const __attribute__((address_space(1))) unsigned int*)(const void*)(g0 + off + lane * 4),
            (__attribute__((address_space(3))) unsigned int*)(void*)(dst + off),
            16, 0, 0);
      }
    }
  } else {
    for (int i = tid; i < TSUB + 64; i += 256) {
      const int g = base - 32 + i;
      dst[i] = (g >= 0 && g < L_) ? xr[g] : 0.0f;  // SAME zero-pad as real taps
    }
  }
}

// ---------------------------------------------------------------- K1 body
template<int KS>
__device__ __forceinline__ void k1_body(
    const float* __restrict__ xr, const float* __restrict__ w,
    float* __restrict__ yrow, u32* __restrict__ gh,
    float* xb0, float* xb1, u32* h32)
{
  constexpr int PAD = KS / 2;
  constexpr int OFF = 32 - PAD;            // staged tile origin is base-32
  const int tid = threadIdx.x;

  float wreg[KS];
#pragma unroll
  for (int j = 0; j < KS; ++j) wreg[j] = w[j];

  for (int i = tid; i < NBINS / 2; i += 256) h32[i] = 0u;

  const int base0 = blockIdx.x * SUBS * TSUB;
  k1_stage(xr, base0, xb0, tid);
  __syncthreads();                          // drains stage0 + h32 zeroing

  for (int it = 0; it < SUBS; ++it) {
    const int base = base0 + it * TSUB;
    if (base >= L_) break;                  // uniform across block
    float* cur = (it & 1) ? xb1 : xb0;
    float* nxt = (it & 1) ? xb0 : xb1;
    const int nbase = base + TSUB;
    if (it + 1 < SUBS && nbase < L_)
      k1_stage(xr, nbase, nxt, tid);        // async; completes under conv

    // ---- conv: 9 outputs/thread, j-ascending fmaf chain (bit-stable)
    float acc[9];
#pragma unroll
    for (int r = 0; r < 9; ++r) acc[r] = 0.0f;
    const int q0 = tid * 9;                 // stride 9 (coprime 32) -> bank-clean
#pragma unroll
    for (int p = 0; p < KS + 8; ++p) {      // sliding window: p = r + j
      float xv = cur[q0 + OFF + p];
#pragma unroll
      for (int r = 0; r < 9; ++r) {
        const int j = p - r;
        if (j >= 0 && j < KS) acc[r] = fmaf(xv, wreg[j], acc[r]);
      }
    }

    // ---- y store: direct from regs (no LDS roundtrip, no extra barrier)
    const int g0 = base + q0;
    if (g0 + 9 <= L_) {
      float* yp = yrow + g0;
#pragma unroll
      for (int r = 0; r < 9; ++r) yp[r] = acc[r];
    } else {
#pragma unroll
      for (int r = 0; r < 9; ++r)
        if (g0 + r < L_) yrow[g0 + r] = acc[r];
    }

    // ---- histogram (packed u16 pairs; per-block total 18432 -> no overflow)
#pragma unroll
    for (int r = 0; r < 9; ++r) {
      if (g0 + r < L_) {
        u32 ab = __float_as_uint(acc[r]) & 0x7fffffffu;
        u32 bin = ab >> 18;
        atomicAdd(&h32[bin >> 1], 1u << (16 * (bin & 1)));
      }
    }
    __syncthreads();   // single barrier: nxt staged, y stores drained, cur free
  }

  // ---- merge histogram
  for (int i = tid; i < NBINS / 2; i += 256) {
    u32 v = h32[i];
    u32 lo = v & 0xffffu, hi = v >> 16;
    if (lo) atomicAdd(&gh[2 * i], lo);
    if (hi) atomicAdd(&gh[2 * i + 1], hi);
  }
}

__global__ __launch_bounds__(256) void k1_hist(
    const float* __restrict__ x, const float* __restrict__ w0,
    const float* __restrict__ w1, const float* __restrict__ w2,
    const float* __restrict__ w3, float* __restrict__ y,
    u32* __restrict__ ghist, int kk0, int ng)
{
  __shared__ __align__(16) float xb[2][XSTG];     // 20 KB double-buffer
  __shared__ u32 h32[NBINS / 2];                  // 16 KB packed u16 hist
  const int kg = blockIdx.y;
  const int row = blockIdx.z;
  const int rkl = row * ng + kg;
  const int kk = kk0 + kg;
  const float* xr = x + (size_t)row * L_;
  float* yrow = y + (size_t)rkl * L_;
  u32* gh = ghist + (size_t)rkl * NBINS;
  switch (kk) {
    case 0:  k1_body<65>(xr, w0, yrow, gh, xb[0], xb[1], h32); break;
    case 1:  k1_body<33>(xr, w1, yrow, gh, xb[0], xb[1], h32); break;
    case 2:  k1_body<17>(xr, w2, yrow, gh, xb[0], xb[1], h32); break;
    default: k1_body< 9>(xr, w3, yrow, gh, xb[0], xb[1], h32); break;
  }
}

// ---------------------------------------------------------------- K3: bin-find + scan
// Bin-find (former k2) recomputed per block from ghist (identical result);
// blockIdx.x==0 publishes bbin/rrem for k4.
__global__ __launch_bounds__(256) void k3_scan(
    const float* __restrict__ y, const u32* __restrict__ ghist,
    u32* __restrict__ bbin, u32* __restrict__ rrem,
    u32* __restrict__ ccount, uint2* __restrict__ cand, int kk0, int ng)
{
  __shared__ u32 h[NBINS];
  __shared__ u32 ssum[256];
  __shared__ uint2 lcand[LCAP];
  __shared__ u32 lmeta[5];   // 0:cnt 1:m 2:wrbase 3:bin 4:(unused)
  const int tid = threadIdx.x;
  const int rkl = blockIdx.z * ng + blockIdx.y;
  const u32 k = (u32)d_K[kk0 + blockIdx.y];
  const u32* gh = ghist + (size_t)rkl * NBINS;
  for (int i = tid; i < NBINS; i += 256) h[i] = gh[i];
  if (tid == 0) lmeta[0] = 0u;
  __syncthreads();
  u32 s = 0;
  for (int i = 0; i < 32; ++i) s += h[tid * 32 + i];
  ssum[tid] = s;
  __syncthreads();
  if (tid == 0) {
    u32 cum = 0; int b = 0;
    for (int t = 255; t >= 0; --t) {       // walk from the top (largest |y|)
      if (cum + ssum[t] >= k) {
        for (int i = t * 32 + 31; i >= t * 32; --i) {
          if (cum + h[i] >= k) { b = i; break; }
          cum += h[i];
        }
        break;
      }
      cum += ssum[t];
    }
    lmeta[3] = (u32)b;
    if (blockIdx.x == 0) { bbin[rkl] = (u32)b; rrem[rkl] = k - cum; }
  }
  __syncthreads();
  const u32 target = lmeta[3];

  const float* yr = y + (size_t)rkl * L_;
  const int c0 = blockIdx.x * (L_ / NSCAN);
  const float4* src = (const float4*)(yr + c0);
  for (int i = tid; i < (L_ / NSCAN) / 4; i += 256) {
    float4 v = src[i];
    const float* vf = (const float*)&v;
#pragma unroll
    for (int c = 0; c < 4; ++c) {
      u32 ab = __float_as_uint(vf[c]) & 0x7fffffffu;
      if ((ab >> 18) == target) {
        u32 slot = atomicAdd(&lmeta[0], 1u);
        if (slot < LCAP) lcand[slot] = make_uint2(ab, (u32)(c0 + 4 * i + c));
      }
    }
  }
  __syncthreads();
  if (tid == 0) {
    u32 m = lmeta[0]; if (m > LCAP) m = LCAP;
    lmeta[1] = m;
    lmeta[2] = atomicAdd(&ccount[rkl], m);
  }
  __syncthreads();
  const u32 m = lmeta[1], bse = lmeta[2];
  uint2* cd = cand + (size_t)rkl * CAPC;
  for (u32 i = tid; i < m; i += 256)
    if (bse + i < CAPC) cd[bse + i] = lcand[i];
}

// ---------------------------------------------------------------- K4: select
__global__ __launch_bounds__(256) void k4_select(
    const uint2* __restrict__ cand, const u32* __restrict__ ccount,
    const u32* __restrict__ bbinA, const u32* __restrict__ rremA,
    u32* __restrict__ thr, u32* __restrict__ keepAll,
    u32* __restrict__ excN, u32* __restrict__ excL)
{
  __shared__ u32 cab[CAPC];
  __shared__ u32 h64[64];
  __shared__ u32 sh[3];
  __shared__ u32 lidx[64];
  __shared__ u32 lcnt;
  const int rkl = blockIdx.x;
  int n = (int)min(ccount[rkl], (u32)CAPC);
  u32 r = rremA[rkl];
  if (r > (u32)n) r = (u32)n;              // overflow fallback (statistically never)
  const uint2* cd = cand + (size_t)rkl * CAPC;
  for (int i = threadIdx.x; i < n; i += 256) cab[i] = cd[i].x & 0x3ffffu;

  u32 sel = 0;
  for (int round = 0; round < 3; ++round) {  // 3 x 6-bit MSD radix select
    const int shift = 12 - 6 * round;
    const u32 himask = (round == 0) ? 0u : ((0x3ffffu << (shift + 6)) & 0x3ffffu);
    if (threadIdx.x < 64) h64[threadIdx.x] = 0u;
    __syncthreads();
    for (int i = threadIdx.x; i < n; i += 256) {
      u32 v = cab[i];
      if ((v & himask) == (sel & himask)) atomicAdd(&h64[(v >> shift) & 63u], 1u);
    }
    __syncthreads();
    if (threadIdx.x == 0) {
      u32 cum = 0; int d = 0;
      for (int dd = 63; dd >= 0; --dd) {
        if (cum + h64[dd] >= r) { d = dd; break; }
        cum += h64[dd];
      }
      sh[0] = (u32)d;
      sh[1] = r - cum;
      sh[2] = h64[d];
    }
    __syncthreads();
    sel |= sh[0] << shift;
    r = sh[1];
  }
  const u32 dup = sh[2];                   // multiplicity of threshold value
  const u32 m = r;                         // how many tied values to keep
  if (threadIdx.x == 0) thr[rkl] = (bbinA[rkl] << 18) | sel;

  if (m >= dup) {
    if (threadIdx.x == 0) { keepAll[rkl] = 1u; excN[rkl] = 0u; }
    return;
  }
  if (threadIdx.x == 0) lcnt = 0u;
  __syncthreads();
  for (int i = threadIdx.x; i < n; i += 256) {
    if (cab[i] == sel) {
      u32 s2 = atomicAdd(&lcnt, 1u);
      if (s2 < 64) lidx[s2] = cd[i].y;
    }
  }
  __syncthreads();
  if (threadIdx.x == 0) {
    int c = (int)min(lcnt, 64u);
    for (int i = 1; i < c; ++i) {          // sort ascending index (top_k tie-break)
      u32 v = lidx[i]; int j = i - 1;
      while (j >= 0 && lidx[j] > v) { lidx[j + 1] = lidx[j]; --j; }
      lidx[j + 1] = v;
    }
    u32 mm = min(m, 32u);
    keepAll[rkl] = 0u; excN[rkl] = mm;
    for (u32 i = 0; i < mm; ++i) excL[(size_t)rkl * 32 + i] = lidx[i];
  }
}

// ---------------------------------------------------------------- K5: final
__device__ __forceinline__ float k5_mask(float yv, int g, u32 t_ab, u32 ka,
                                         u32 en, const u32* __restrict__ excp)
{
  u32 ab = __float_as_uint(yv) & 0x7fffffffu;
  bool keep = ab > t_ab;
  if (ab == t_ab) {                        // threshold ties: exact top_k semantics
    if (ka) keep = true;
    else {
      for (u32 e = 0; e < en; ++e)
        if (excp[e] == (u32)g) { keep = true; break; }
    }
  }
  return keep ? yv : 0.0f;
}

template<int KS>
__device__ __forceinline__ void k5_conv(
    const float* __restrict__ w, const float* abuf, float* accO)
{
  constexpr int PAD = KS / 2;
  constexpr int OFF2 = 32 - PAD;
  float wreg[KS];
#pragma unroll
  for (int j = 0; j < KS; ++j) wreg[j] = w[j];
  const int o0 = threadIdx.x * 9;
#pragma unroll
  for (int p = 0; p < KS + 8; ++p) {
    float av = abuf[o0 + OFF2 + p];
#pragma unroll
    for (int r = 0; r < 9; ++r) {
      const int j = p - r;
      if (j >= 0 && j < KS) accO[r] = fmaf(av, wreg[j], accO[r]);
    }
  }
}

__global__ __launch_bounds__(256) void k5_final(
    const float* __restrict__ y, const float* __restrict__ w0,
    const float* __restrict__ w1, const float* __restrict__ w2,
    const float* __restrict__ w3, const u32* __restrict__ thr,
    const u32* __restrict__ keepAll, const u32* __restrict__ excN,
    const u32* __restrict__ excL, float* __restrict__ out,
    int kk0, int ng)
{
  __shared__ __align__(16) float abuf[T5 + 64];
  const int tid = threadIdx.x;
  const int row = blockIdx.y;
  const int tile0 = blockIdx.x * T5;
  float accO[9];
#pragma unroll
  for (int r = 0; r < 9; ++r) accO[r] = 0.0f;

  for (int kg = 0; kg < ng; ++kg) {
    const int rkl = row * ng + kg;
    const int kk = kk0 + kg;
    const u32 t_ab = thr[rkl], ka = keepAll[rkl], en = excN[rkl];
    const u32* excp = excL + (size_t)rkl * 32;
    const float* yr = y + (size_t)rkl * L_;
    // stage masked activations on [tile0-32, tile0+T5+32)
    const bool interior = (tile0 >= 32) && (tile0 + T5 + 32 <= L_);
    if (interior) {
      const float4* src = (const float4*)(yr + tile0 - 32);
      for (int i = tid; i < (T5 + 64) / 4; i += 256) {
        float4 v = src[i];
        float* vf = (float*)&v;
#pragma unroll
        for (int c = 0; c < 4; ++c)
          vf[c] = k5_mask(vf[c], tile0 - 32 + 4 * i + c, t_ab, ka, en, excp);
        ((float4*)abuf)[i] = v;
      }
    } else {
      for (int i = tid; i < T5 + 64; i += 256) {
        int g = tile0 - 32 + i;
        float av = 0.0f;
        if (g >= 0 && g < L_) av = k5_mask(yr[g], g, t_ab, ka, en, excp);
        abuf[i] = av;
      }
    }
    __syncthreads();
    switch (kk) {
      case 0:  k5_conv<65>(w0, abuf, accO); break;
      case 1:  k5_conv<33>(w1, abuf, accO); break;
      case 2:  k5_conv<17>(w2, abuf, accO); break;
      default: k5_conv< 9>(w3, abuf, accO); break;
    }
    __syncthreads();                       // abuf reused by next kg
  }

  // direct out write from regs (9 consecutive floats/thread)
  const int g0 = tile0 + tid * 9;
  float* orow = out + (size_t)row * L_;
  if (kk0 == 0) {
    if (g0 + 9 <= L_) {
      float* op = orow + g0;
#pragma unroll
      for (int r = 0; r < 9; ++r) op[r] = accO[r];
    } else {
#pragma unroll
      for (int r = 0; r < 9; ++r)
        if (g0 + r < L_) orow[g0 + r] = accO[r];
    }
  } else {
    if (g0 + 9 <= L_) {
      float* op = orow + g0;
#pragma unroll
      for (int r = 0; r < 9; ++r) op[r] += accO[r];
    } else {
#pragma unroll
      for (int r = 0; r < 9; ++r)
        if (g0 + r < L_) orow[g0 + r] += accO[r];
    }
  }
}

// ---------------------------------------------------------------- host
extern "C" void kernel_launch(void* const* d_in, const int* in_sizes, int n_in,
                              void* d_out, int out_size, void* d_ws, size_t ws_size,
                              hipStream_t stream)
{
  (void)in_sizes; (void)n_in; (void)out_size;
  const float* x  = (const float*)d_in[0];
  const float* w0 = (const float*)d_in[1];
  const float* w1 = (const float*)d_in[2];
  const float* w2 = (const float*)d_in[3];
  const float* w3 = (const float*)d_in[4];
  float* out = (float*)d_out;

  // per-group ws need: y + ghist + ccount + bbin/rrem/thr/kAll/excN + excL + cand
  auto need = [](int ng) -> size_t {
    return (size_t)ng * 64 * ((size_t)L_ * 4 + NBINS * 4 + 4 * 6 + 32 * 4 + CAPC * 8);
  };
  int ng = 1;
  if (ws_size >= need(4)) ng = 4;
  else if (ws_size >= need(2)) ng = 2;

  const size_t NRK = (size_t)64 * ng;
  float* y     = (float*)d_ws;
  u32* ghist   = (u32*)(y + NRK * L_);
  u32* ccount  = ghist + NRK * NBINS;
  u32* bbin    = ccount + NRK;
  u32* rrem    = bbin + NRK;
  u32* thr     = rrem + NRK;
  u32* kAll    = thr + NRK;
  u32* excN    = kAll + NRK;
  u32* excL    = excN + NRK;               // NRK*32
  uint2* cand  = (uint2*)(excL + NRK * 32);

  for (int kk0 = 0; kk0 < 4; kk0 += ng) {
    hipMemsetAsync(ghist, 0, (NRK * NBINS + NRK) * sizeof(u32), stream);  // ghist+ccount
    dim3 g1(NCHUNK, ng, B_);
    k1_hist<<<g1, 256, 0, stream>>>(x, w0, w1, w2, w3, y, ghist, kk0, ng);
    dim3 g3(NSCAN, ng, B_);
    k3_scan<<<g3, 256, 0, stream>>>(y, ghist, bbin, rrem, ccount, cand, kk0, ng);
    k4_select<<<(int)NRK, 256, 0, stream>>>(cand, ccount, bbin, rrem, thr, kAll, excN, excL);
    dim3 g5(NT5, B_);
    k5_final<<<g5, 256, 0, stream>>>(y, w0, w1, w2, w3, thr, kAll, excN, excL, out, kk0, ng);
  }
}

// Round 8
// 436.397 us; speedup vs baseline: 2.7216x; 1.1522x over previous
//
#include <hip/hip_runtime.h>
#include <stdint.h>

// SAN1d: 4x { y = conv_same(x,w); a = topk_abs(y,k); out += conv_same(a,w) }
// B=64 rows, L=262144, ks={65,33,17,9}, k=L//ks.
//
// R8 (profile-driven): R7 showed KS-independent k1 time + k5 regression ->
// scattered 9-float/thread global stores (36B lane stride, ~9x L2 write
// transactions) were the bottleneck. Now ALL global stores are coalesced
// float4 via LDS transpose: k1 gets a double-buffered ybuf flushed under the
// next subtile's conv (still ONE barrier/subtile); histogram moves out of k1
// into a BW-bound y-scan kernel (k1 LDS 38.9KB -> 4 blocks/CU, pure pipeline);
// k5 restores the R4 transpose epilogue.

#define B_ 64
#define L_ 262144
#define NBINS 8192      // |y| bits >> 18  (13 bits: exponent + 5 mantissa)
#define CAPC 8192       // candidate cap per (row,kernel); expected max ~2k
#define LCAP 1024       // per-block local candidate cap
#define TSUB 2304       // 256 threads * 9 outputs
#define SUBS 8          // subtiles per K1 block
#define NCHUNK 15       // ceil(L / (TSUB*SUBS))
#define XSTG 2560       // staged x tile incl. halo + gload granularity pad
#define T5 2304         // K5 tile
#define NT5 114         // ceil(L / T5)
#define NSCAN 16        // y-scan blocks per (row,kernel); L/NSCAN = 16384

typedef unsigned int u32;

__device__ const int d_K[4] = {4032, 7943, 15420, 29127};  // L_ // ks

// ---------------------------------------------------------------- K1 staging
// Interior: async global->LDS, 16B/lane, wave-uniform LDS base (+lane*16 by HW).
// Pad region [2368,2560) may hold garbage row data; conv never reads it.
__device__ __forceinline__ void k1_stage(const float* __restrict__ xr, int base,
                                         float* dst, int tid)
{
  const bool interior = (base >= 32) && (base - 32 + XSTG <= L_);
  if (interior) {
    const float* g0 = xr + (base - 32);
    const int wv = tid >> 6, lane = tid & 63;
#pragma unroll
    for (int r = 0; r < 3; ++r) {
      const int off = (r * 4 + wv) * 256;          // floats; wave-uniform
      if (off < XSTG) {
        __builtin_amdgcn_global_load_lds(
            (const __attribute__((address_space(1))) unsigned int*)(const void*)(g0 + off + lane * 4),
            (__attribute__((address_space(3))) unsigned int*)(void*)(dst + off),
            16, 0, 0);
      }
    }
  } else {
    for (int i = tid; i < TSUB + 64; i += 256) {
      const int g = base - 32 + i;
      dst[i] = (g >= 0 && g < L_) ? xr[g] : 0.0f;  // SAME zero-pad as real taps
    }
  }
}

// ---------------------------------------------------------------- K1 body
template<int KS>
__device__ __forceinline__ void k1_body(
    const float* __restrict__ xr, const float* __restrict__ w,
    float* __restrict__ yrow,
    float* xb0, float* xb1, float* yb0, float* yb1)
{
  constexpr int PAD = KS / 2;
  constexpr int OFF = 32 - PAD;            // staged tile origin is base-32
  const int tid = threadIdx.x;

  float wreg[KS];
#pragma unroll
  for (int j = 0; j < KS; ++j) wreg[j] = w[j];

  const int base0 = blockIdx.x * SUBS * TSUB;
  k1_stage(xr, base0, xb0, tid);
  __syncthreads();                          // stage0 complete

  int pendBase = -1;
  float* pendBuf = nullptr;

  for (int it = 0; it < SUBS; ++it) {
    const int base = base0 + it * TSUB;
    if (base >= L_) break;                  // uniform across block
    float* xcur = (it & 1) ? xb1 : xb0;
    float* xnxt = (it & 1) ? xb0 : xb1;
    float* ycur = (it & 1) ? yb1 : yb0;
    const int nbase = base + TSUB;
    if (it + 1 < SUBS && nbase < L_)
      k1_stage(xr, nbase, xnxt, tid);       // async; completes under conv

    // ---- flush previous subtile's y: coalesced float4 (hidden under conv)
    if (pendBase >= 0) {
      const int n4 = min(TSUB, L_ - pendBase) >> 2;
      float4* dst = (float4*)(yrow + pendBase);
      for (int i = tid; i < n4; i += 256) dst[i] = ((const float4*)pendBuf)[i];
    }

    // ---- conv: 9 outputs/thread, j-ascending fmaf chain (bit-stable)
    float acc[9];
#pragma unroll
    for (int r = 0; r < 9; ++r) acc[r] = 0.0f;
    const int q0 = tid * 9;                 // stride 9 (coprime 32) -> bank-clean
#pragma unroll
    for (int p = 0; p < KS + 8; ++p) {      // sliding window: p = r + j
      float xv = xcur[q0 + OFF + p];
#pragma unroll
      for (int r = 0; r < 9; ++r) {
        const int j = p - r;
        if (j >= 0 && j < KS) acc[r] = fmaf(xv, wreg[j], acc[r]);
      }
    }

    // ---- y -> LDS ybuf (stride-9 writes, bank-clean)
#pragma unroll
    for (int r = 0; r < 9; ++r) ycur[q0 + r] = acc[r];
    pendBase = base; pendBuf = ycur;
    __syncthreads();  // single barrier: xnxt staged, ycur visible, flush reads done
  }

  // ---- epilogue flush
  if (pendBase >= 0) {
    const int n4 = min(TSUB, L_ - pendBase) >> 2;
    float4* dst = (float4*)(yrow + pendBase);
    for (int i = tid; i < n4; i += 256) dst[i] = ((const float4*)pendBuf)[i];
  }
}

__global__ __launch_bounds__(256) void k1_conv(
    const float* __restrict__ x, const float* __restrict__ w0,
    const float* __restrict__ w1, const float* __restrict__ w2,
    const float* __restrict__ w3, float* __restrict__ y,
    int kk0, int ng)
{
  __shared__ __align__(16) float xb[2][XSTG];     // 20 KB x double-buffer
  __shared__ __align__(16) float yb[2][TSUB];     // 18.4 KB y double-buffer
  const int kg = blockIdx.y;
  const int row = blockIdx.z;
  const int rkl = row * ng + kg;
  const int kk = kk0 + kg;
  const float* xr = x + (size_t)row * L_;
  float* yrow = y + (size_t)rkl * L_;
  switch (kk) {
    case 0:  k1_body<65>(xr, w0, yrow, xb[0], xb[1], yb[0], yb[1]); break;
    case 1:  k1_body<33>(xr, w1, yrow, xb[0], xb[1], yb[0], yb[1]); break;
    case 2:  k1_body<17>(xr, w2, yrow, xb[0], xb[1], yb[0], yb[1]); break;
    default: k1_body< 9>(xr, w3, yrow, xb[0], xb[1], yb[0], yb[1]); break;
  }
}

// ---------------------------------------------------------------- K2a: hist from y
__global__ __launch_bounds__(256) void k2_hist(
    const float* __restrict__ y, u32* __restrict__ ghist, int ng)
{
  __shared__ u32 h32[NBINS / 2];           // 16 KB packed u16 hist
  const int tid = threadIdx.x;
  const int rkl = blockIdx.z * ng + blockIdx.y;
  for (int i = tid; i < NBINS / 2; i += 256) h32[i] = 0u;
  __syncthreads();
  const float* yr = y + (size_t)rkl * L_;
  const int c0 = blockIdx.x * (L_ / NSCAN);
  const float4* src = (const float4*)(yr + c0);
  for (int i = tid; i < (L_ / NSCAN) / 4; i += 256) {
    float4 v = src[i];
    const float* vf = (const float*)&v;
#pragma unroll
    for (int c = 0; c < 4; ++c) {
      u32 bin = (__float_as_uint(vf[c]) & 0x7fffffffu) >> 18;
      atomicAdd(&h32[bin >> 1], 1u << (16 * (bin & 1)));   // 16384/block max
    }
  }
  __syncthreads();
  u32* gh = ghist + (size_t)rkl * NBINS;
  for (int i = tid; i < NBINS / 2; i += 256) {
    u32 v = h32[i];
    u32 lo = v & 0xffffu, hi = v >> 16;
    if (lo) atomicAdd(&gh[2 * i], lo);
    if (hi) atomicAdd(&gh[2 * i + 1], hi);
  }
}

// ---------------------------------------------------------------- K2b: bin find
__global__ __launch_bounds__(256) void k2_findbin(
    const u32* __restrict__ ghist, u32* __restrict__ bbin, u32* __restrict__ rrem,
    int kk0, int ng)
{
  __shared__ u32 h[NBINS];
  __shared__ u32 ssum[256];
  const int rkl = blockIdx.x;
  const u32 k = (u32)d_K[kk0 + (rkl % ng)];
  const u32* gh = ghist + (size_t)rkl * NBINS;
  for (int i = threadIdx.x; i < NBINS; i += 256) h[i] = gh[i];
  __syncthreads();
  u32 s = 0;
  for (int i = 0; i < 32; ++i) s += h[threadIdx.x * 32 + i];
  ssum[threadIdx.x] = s;
  __syncthreads();
  if (threadIdx.x == 0) {
    u32 cum = 0; int b = 0;
    for (int t = 255; t >= 0; --t) {       // walk from the top (largest |y|)
      if (cum + ssum[t] >= k) {
        for (int i = t * 32 + 31; i >= t * 32; --i) {
          if (cum + h[i] >= k) { b = i; break; }
          cum += h[i];
        }
        break;
      }
      cum += ssum[t];
    }
    bbin[rkl] = (u32)b;
    rrem[rkl] = k - cum;                   // 1-based rank inside bin b
  }
}

// ---------------------------------------------------------------- K3: scan y
__global__ __launch_bounds__(256) void k3_scan(
    const float* __restrict__ y, const u32* __restrict__ bbin,
    u32* __restrict__ ccount, uint2* __restrict__ cand, int ng)
{
  __shared__ uint2 lcand[LCAP];
  __shared__ u32 lmeta[3];
  const int tid = threadIdx.x;
  const int rkl = blockIdx.z * ng + blockIdx.y;
  const u32 target = bbin[rkl];
  if (tid == 0) lmeta[0] = 0u;
  __syncthreads();
  const float* yr = y + (size_t)rkl * L_;
  const int c0 = blockIdx.x * (L_ / NSCAN);
  const float4* src = (const float4*)(yr + c0);
  for (int i = tid; i < (L_ / NSCAN) / 4; i += 256) {
    float4 v = src[i];
    const float* vf = (const float*)&v;
#pragma unroll
    for (int c = 0; c < 4; ++c) {
      u32 ab = __float_as_uint(vf[c]) & 0x7fffffffu;
      if ((ab >> 18) == target) {
        u32 slot = atomicAdd(&lmeta[0], 1u);
        if (slot < LCAP) lcand[slot] = make_uint2(ab, (u32)(c0 + 4 * i + c));
      }
    }
  }
  __syncthreads();
  if (tid == 0) {
    u32 m = lmeta[0]; if (m > LCAP) m = LCAP;
    lmeta[1] = m;
    lmeta[2] = atomicAdd(&ccount[rkl], m);
  }
  __syncthreads();
  const u32 m = lmeta[1], bse = lmeta[2];
  uint2* cd = cand + (size_t)rkl * CAPC;
  for (u32 i = tid; i < m; i += 256)
    if (bse + i < CAPC) cd[bse + i] = lcand[i];
}

// ---------------------------------------------------------------- K4: select
__global__ __launch_bounds__(256) void k4_select(
    const uint2* __restrict__ cand, const u32* __restrict__ ccount,
    const u32* __restrict__ bbinA, const u32* __restrict__ rremA,
    u32* __restrict__ thr, u32* __restrict__ keepAll,
    u32* __restrict__ excN, u32* __restrict__ excL)
{
  __shared__ u32 cab[CAPC];
  __shared__ u32 h64[64];
  __shared__ u32 sh[3];
  __shared__ u32 lidx[64];
  __shared__ u32 lcnt;
  const int rkl = blockIdx.x;
  int n = (int)min(ccount[rkl], (u32)CAPC);
  u32 r = rremA[rkl];
  if (r > (u32)n) r = (u32)n;              // overflow fallback (statistically never)
  const uint2* cd = cand + (size_t)rkl * CAPC;
  for (int i = threadIdx.x; i < n; i += 256) cab[i] = cd[i].x & 0x3ffffu;

  u32 sel = 0;
  for (int round = 0; round < 3; ++round) {  // 3 x 6-bit MSD radix select
    const int shift = 12 - 6 * round;
    const u32 himask = (round == 0) ? 0u : ((0x3ffffu << (shift + 6)) & 0x3ffffu);
    if (threadIdx.x < 64) h64[threadIdx.x] = 0u;
    __syncthreads();
    for (int i = threadIdx.x; i < n; i += 256) {
      u32 v = cab[i];
      if ((v & himask) == (sel & himask)) atomicAdd(&h64[(v >> shift) & 63u], 1u);
    }
    __syncthreads();
    if (threadIdx.x == 0) {
      u32 cum = 0; int d = 0;
      for (int dd = 63; dd >= 0; --dd) {
        if (cum + h64[dd] >= r) { d = dd; break; }
        cum += h64[dd];
      }
      sh[0] = (u32)d;
      sh[1] = r - cum;
      sh[2] = h64[d];
    }
    __syncthreads();
    sel |= sh[0] << shift;
    r = sh[1];
  }
  const u32 dup = sh[2];                   // multiplicity of threshold value
  const u32 m = r;                         // how many tied values to keep
  if (threadIdx.x == 0) thr[rkl] = (bbinA[rkl] << 18) | sel;

  if (m >= dup) {
    if (threadIdx.x == 0) { keepAll[rkl] = 1u; excN[rkl] = 0u; }
    return;
  }
  if (threadIdx.x == 0) lcnt = 0u;
  __syncthreads();
  for (int i = threadIdx.x; i < n; i += 256) {
    if (cab[i] == sel) {
      u32 s2 = atomicAdd(&lcnt, 1u);
      if (s2 < 64) lidx[s2] = cd[i].y;
    }
  }
  __syncthreads();
  if (threadIdx.x == 0) {
    int c = (int)min(lcnt, 64u);
    for (int i = 1; i < c; ++i) {          // sort ascending index (top_k tie-break)
      u32 v = lidx[i]; int j = i - 1;
      while (j >= 0 && lidx[j] > v) { lidx[j + 1] = lidx[j]; --j; }
      lidx[j + 1] = v;
    }
    u32 mm = min(m, 32u);
    keepAll[rkl] = 0u; excN[rkl] = mm;
    for (u32 i = 0; i < mm; ++i) excL[(size_t)rkl * 32 + i] = lidx[i];
  }
}

// ---------------------------------------------------------------- K5: final
__device__ __forceinline__ float k5_mask(float yv, int g, u32 t_ab, u32 ka,
                                         u32 en, const u32* __restrict__ excp)
{
  u32 ab = __float_as_uint(yv) & 0x7fffffffu;
  bool keep = ab > t_ab;
  if (ab == t_ab) {                        // threshold ties: exact top_k semantics
    if (ka) keep = true;
    else {
      for (u32 e = 0; e < en; ++e)
        if (excp[e] == (u32)g) { keep = true; break; }
    }
  }
  return keep ? yv : 0.0f;
}

template<int KS>
__device__ __forceinline__ void k5_conv(
    const float* __restrict__ w, const float* abuf, float* accO)
{
  constexpr int PAD = KS / 2;
  constexpr int OFF2 = 32 - PAD;
  float wreg[KS];
#pragma unroll
  for (int j = 0; j < KS; ++j) wreg[j] = w[j];
  const int o0 = threadIdx.x * 9;
#pragma unroll
  for (int p = 0; p < KS + 8; ++p) {
    float av = abuf[o0 + OFF2 + p];
#pragma unroll
    for (int r = 0; r < 9; ++r) {
      const int j = p - r;
      if (j >= 0 && j < KS) accO[r] = fmaf(av, wreg[j], accO[r]);
    }
  }
}

__global__ __launch_bounds__(256) void k5_final(
    const float* __restrict__ y, const float* __restrict__ w0,
    const float* __restrict__ w1, const float* __restrict__ w2,
    const float* __restrict__ w3, const u32* __restrict__ thr,
    const u32* __restrict__ keepAll, const u32* __restrict__ excN,
    const u32* __restrict__ excL, float* __restrict__ out,
    int kk0, int ng)
{
  __shared__ __align__(16) float abuf[T5 + 64];
  const int tid = threadIdx.x;
  const int row = blockIdx.y;
  const int tile0 = blockIdx.x * T5;
  float accO[9];
#pragma unroll
  for (int r = 0; r < 9; ++r) accO[r] = 0.0f;

  for (int kg = 0; kg < ng; ++kg) {
    const int rkl = row * ng + kg;
    const int kk = kk0 + kg;
    const u32 t_ab = thr[rkl], ka = keepAll[rkl], en = excN[rkl];
    const u32* excp = excL + (size_t)rkl * 32;
    const float* yr = y + (size_t)rkl * L_;
    // stage masked activations on [tile0-32, tile0+T5+32)
    const bool interior = (tile0 >= 32) && (tile0 + T5 + 32 <= L_);
    if (interior) {
      const float4* src = (const float4*)(yr + tile0 - 32);
      for (int i = tid; i < (T5 + 64) / 4; i += 256) {
        float4 v = src[i];
        float* vf = (float*)&v;
#pragma unroll
        for (int c = 0; c < 4; ++c)
          vf[c] = k5_mask(vf[c], tile0 - 32 + 4 * i + c, t_ab, ka, en, excp);
        ((float4*)abuf)[i] = v;
      }
    } else {
      for (int i = tid; i < T5 + 64; i += 256) {
        int g = tile0 - 32 + i;
        float av = 0.0f;
        if (g >= 0 && g < L_) av = k5_mask(yr[g], g, t_ab, ka, en, excp);
        abuf[i] = av;
      }
    }
    __syncthreads();
    switch (kk) {
      case 0:  k5_conv<65>(w0, abuf, accO); break;
      case 1:  k5_conv<33>(w1, abuf, accO); break;
      case 2:  k5_conv<17>(w2, abuf, accO); break;
      default: k5_conv< 9>(w3, abuf, accO); break;
    }
    __syncthreads();                       // abuf reused by next kg
  }

  // LDS transpose -> coalesced float4 out write (RMW on later passes)
  const int o0 = tid * 9;
#pragma unroll
  for (int r = 0; r < 9; ++r) abuf[o0 + r] = accO[r];
  __syncthreads();
  float* orow = out + (size_t)row * L_ + tile0;
  const int n4 = min(T5, L_ - tile0) / 4;
  if (kk0 == 0) {
    for (int i = tid; i < n4; i += 256)
      ((float4*)orow)[i] = ((const float4*)abuf)[i];
  } else {
    for (int i = tid; i < n4; i += 256) {
      float4 p = ((const float4*)orow)[i];
      float4 a = ((const float4*)abuf)[i];
      p.x += a.x; p.y += a.y; p.z += a.z; p.w += a.w;
      ((float4*)orow)[i] = p;
    }
  }
}

// ---------------------------------------------------------------- host
extern "C" void kernel_launch(void* const* d_in, const int* in_sizes, int n_in,
                              void* d_out, int out_size, void* d_ws, size_t ws_size,
                              hipStream_t stream)
{
  (void)in_sizes; (void)n_in; (void)out_size;
  const float* x  = (const float*)d_in[0];
  const float* w0 = (const float*)d_in[1];
  const float* w1 = (const float*)d_in[2];
  const float* w2 = (const float*)d_in[3];
  const float* w3 = (const float*)d_in[4];
  float* out = (float*)d_out;

  // per-group ws need: y + ghist + ccount + bbin/rrem/thr/kAll/excN + excL + cand
  auto need = [](int ng) -> size_t {
    return (size_t)ng * 64 * ((size_t)L_ * 4 + NBINS * 4 + 4 * 6 + 32 * 4 + CAPC * 8);
  };
  int ng = 1;
  if (ws_size >= need(4)) ng = 4;
  else if (ws_size >= need(2)) ng = 2;

  const size_t NRK = (size_t)64 * ng;
  float* y     = (float*)d_ws;
  u32* ghist   = (u32*)(y + NRK * L_);
  u32* ccount  = ghist + NRK * NBINS;
  u32* bbin    = ccount + NRK;
  u32* rrem    = bbin + NRK;
  u32* thr     = rrem + NRK;
  u32* kAll    = thr + NRK;
  u32* excN    = kAll + NRK;
  u32* excL    = excN + NRK;               // NRK*32
  uint2* cand  = (uint2*)(excL + NRK * 32);

  for (int kk0 = 0; kk0 < 4; kk0 += ng) {
    hipMemsetAsync(ghist, 0, (NRK * NBINS + NRK) * sizeof(u32), stream);  // ghist+ccount
    dim3 g1(NCHUNK, ng, B_);
    k1_conv<<<g1, 256, 0, stream>>>(x, w0, w1, w2, w3, y, kk0, ng);
    dim3 gh(NSCAN, ng, B_);
    k2_hist<<<gh, 256, 0, stream>>>(y, ghist, ng);
    k2_findbin<<<(int)NRK, 256, 0, stream>>>(ghist, bbin, rrem, kk0, ng);
    dim3 g3(NSCAN, ng, B_);
    k3_scan<<<g3, 256, 0, stream>>>(y, bbin, ccount, cand, ng);
    k4_select<<<(int)NRK, 256, 0, stream>>>(cand, ccount, bbin, rrem, thr, kAll, excN, excL);
    dim3 g5(NT5, B_);
    k5_final<<<g5, 256, 0, stream>>>(y, w0, w1, w2, w3, thr, kAll, excN, excL, out, kk0, ng);
  }
}